// Round 1
// baseline (6377.459 us; speedup 1.0000x reference)
//
#include <hip/hip_runtime.h>
#include <hip/hip_bf16.h>
#include <math.h>

#define NN 50000
#define DD 128
#define RR 16
#define NBASIS 10
#define NE 1600000
#define NREL 17            // 16 relations + time pseudo-relation
#define DECAY 0.1f
#define KROWS 2304         // 17*128 (rels+time) + 128 (root)

// ---------------- reduction-slot init ----------------
__global__ void k_init(unsigned* red) {
    if (threadIdx.x == 0) {
        red[0] = 0u;              // max(t) bits   (t >= 0 so uint order == float order)
        red[1] = 0x7F800000u;     // min(t) bits = +inf
        ((float*)red)[2] = 0.0f;  // sum of unnormalized w
    }
}

// ---------------- max/min over edge_time ----------------
__global__ void k_minmax(const float* __restrict__ t, unsigned* red) {
    float mx = 0.0f, mn = 1e30f;
    int stride = gridDim.x * blockDim.x;
    for (int i = blockIdx.x * blockDim.x + threadIdx.x; i < NE; i += stride) {
        float v = t[i];
        mx = fmaxf(mx, v);
        mn = fminf(mn, v);
    }
    for (int o = 32; o >= 1; o >>= 1) {
        mx = fmaxf(mx, __shfl_down(mx, o, 64));
        mn = fminf(mn, __shfl_down(mn, o, 64));
    }
    if ((threadIdx.x & 63) == 0) {
        atomicMax(&red[0], __float_as_uint(mx));
        atomicMin(&red[1], __float_as_uint(mn));
    }
}

// ---------------- sum of exp weights ----------------
__global__ void k_sumw(const float* __restrict__ t, unsigned* red) {
    float tmax = __uint_as_float(red[0]);
    float tmin = __uint_as_float(red[1]);
    float rtd  = 1.0f / (tmax - tmin + 1e-8f);
    float s = 0.0f;
    int stride = gridDim.x * blockDim.x;
    for (int i = blockIdx.x * blockDim.x + threadIdx.x; i < NE; i += stride) {
        s += expf(-DECAY * (tmax - t[i]) * rtd);
    }
    for (int o = 32; o >= 1; o >>= 1) s += __shfl_down(s, o, 64);
    if ((threadIdx.x & 63) == 0) atomicAdd(((float*)red) + 2, s);
}

// ---------------- build stacked B matrix [KROWS x 128] ----------------
// rows r*128+d, r in 0..15 : W[r][d][j] = sum_b comp[r,b]*basis[b,d,j]
// rows 2048..2175          : tp_w[d][j]   (time pseudo-relation 16)
// rows 2176..2303          : root[d][j]
__global__ void k_buildB(const float* __restrict__ basis, const float* __restrict__ comp,
                         const float* __restrict__ root,  const float* __restrict__ tp_w,
                         float* __restrict__ B) {
    int idx = blockIdx.x * blockDim.x + threadIdx.x;
    if (idx >= KROWS * DD) return;
    int k = idx >> 7, j = idx & 127;
    float v;
    if (k < RR * DD) {
        int r = k >> 7, d = k & 127;
        v = 0.0f;
        for (int b = 0; b < NBASIS; ++b)
            v = fmaf(comp[r * NBASIS + b], basis[(b * DD + d) * DD + j], v);
    } else if (k < NREL * DD) {
        int d = k - RR * DD;
        v = tp_w[d * DD + j];
    } else {
        int d = k - NREL * DD;
        v = root[d * DD + j];
    }
    B[idx] = v;
}

// ---------------- scatter-aggregate into A [NN x Cc x 128] ----------------
// 32 lanes per edge, float4 per lane. Relations [r0, r1); time path in last chunk.
__global__ __launch_bounds__(256) void k_scatter(
    const float* __restrict__ x, const int* __restrict__ esrc, const int* __restrict__ edst,
    const int* __restrict__ etype, const float* __restrict__ etime,
    const unsigned* __restrict__ red, float* __restrict__ A,
    float* __restrict__ cnt, float* __restrict__ deg,
    int r0, int r1, int Cc)
{
    int slot = threadIdx.x >> 5;
    int lane = threadIdx.x & 31;
    long long e = (long long)blockIdx.x * 8 + slot;
    if (e >= NE) return;
    int rel = etype[e];
    bool doTime = (r1 == NREL);
    bool doRel  = (rel >= r0) && (rel < r1) && (rel < RR);
    if (!doRel && !doTime) return;
    int src = esrc[e], dst = edst[e];
    const float4 xv = ((const float4*)(x + (long long)src * DD))[lane];
    if (doRel) {
        float* p = A + ((long long)dst * Cc + (rel - r0)) * DD + lane * 4;
        atomicAdd(p + 0, xv.x);
        atomicAdd(p + 1, xv.y);
        atomicAdd(p + 2, xv.z);
        atomicAdd(p + 3, xv.w);
        if (lane == 0) atomicAdd(&cnt[dst * RR + rel], 1.0f);
    }
    if (doTime) {
        float tmax = __uint_as_float(red[0]);
        float tmin = __uint_as_float(red[1]);
        float w = expf(-DECAY * (tmax - etime[e]) / (tmax - tmin + 1e-8f));
        float* p = A + ((long long)dst * Cc + (RR - r0)) * DD + lane * 4;
        atomicAdd(p + 0, w * xv.x);
        atomicAdd(p + 1, w * xv.y);
        atomicAdd(p + 2, w * xv.z);
        atomicAdd(p + 3, w * xv.w);
        if (lane == 0) atomicAdd(&deg[dst], 1.0f);
    }
}

// ---------------- tiled fp32 GEMM: acc[n,j] (+)= sum_k Abar[n,k]*B[kb+k][j] ----------------
// Block tile 128 nodes x 128 cols, K-tile 32. Per-thread 8x8 register tile.
// scale_mode==1: per-(n,r) scaling applied during A staging (1/max(cnt,1) or sw/max(deg,1)).
#define GBN 128
#define GKT 32

__global__ __launch_bounds__(256) void k_gemm(
    float* __restrict__ acc, const float* __restrict__ Asrc, int strideA,
    const float* __restrict__ B, int kb, int K,
    const float* __restrict__ cnt, const float* __restrict__ deg,
    const float* __restrict__ redf, int scale_mode, int accumulate)
{
    __shared__ float Ash[GKT][GBN];
    __shared__ float Bsh[GKT][DD];

    const int tid = threadIdx.x;
    const int n0 = blockIdx.x * GBN;
    const int tn = tid >> 4;   // 0..15 -> nodes tn*8 .. tn*8+7
    const int tj = tid & 15;   // 0..15 -> cols  tj*8 .. tj*8+7

    float accr[8][8];
#pragma unroll
    for (int i = 0; i < 8; ++i)
#pragma unroll
        for (int j = 0; j < 8; ++j) accr[i][j] = 0.0f;

    const float sw = 1.0f / (redf[2] + 1e-8f);

    const int nA  = tid >> 1;          // 0..127
    const int kA0 = (tid & 1) * 16;    // 0 or 16
    const int kB  = tid >> 3;          // 0..31
    const int jB  = (tid & 7) * 16;

    for (int kt0 = 0; kt0 < K; kt0 += GKT) {
        __syncthreads();
        // ---- stage A (with inline normalization) ----
        {
            int n = n0 + nA;
            float vals[16];
            if (n < NN) {
                const float* ap = Asrc + (long long)n * strideA + kt0 + kA0;
                const float4 v0 = ((const float4*)ap)[0];
                const float4 v1 = ((const float4*)ap)[1];
                const float4 v2 = ((const float4*)ap)[2];
                const float4 v3 = ((const float4*)ap)[3];
                vals[0]=v0.x; vals[1]=v0.y; vals[2]=v0.z; vals[3]=v0.w;
                vals[4]=v1.x; vals[5]=v1.y; vals[6]=v1.z; vals[7]=v1.w;
                vals[8]=v2.x; vals[9]=v2.y; vals[10]=v2.z; vals[11]=v2.w;
                vals[12]=v3.x; vals[13]=v3.y; vals[14]=v3.z; vals[15]=v3.w;
                if (scale_mode) {
                    int r = (kb + kt0 + kA0) >> 7;   // all 16 ks share one relation block
                    float s;
                    if (r < RR) s = 1.0f / fmaxf(cnt[(long long)n * RR + r], 1.0f);
                    else        s = sw / fmaxf(deg[n], 1.0f);
#pragma unroll
                    for (int i = 0; i < 16; ++i) vals[i] *= s;
                }
            } else {
#pragma unroll
                for (int i = 0; i < 16; ++i) vals[i] = 0.0f;
            }
#pragma unroll
            for (int i = 0; i < 16; ++i) Ash[kA0 + i][nA] = vals[i];
        }
        // ---- stage B ----
        {
            const float* bp = B + (long long)(kb + kt0 + kB) * DD + jB;
            float4 b0 = ((const float4*)bp)[0];
            float4 b1 = ((const float4*)bp)[1];
            float4 b2 = ((const float4*)bp)[2];
            float4 b3 = ((const float4*)bp)[3];
            float4* sp = (float4*)&Bsh[kB][jB];
            sp[0] = b0; sp[1] = b1; sp[2] = b2; sp[3] = b3;
        }
        __syncthreads();
        // ---- compute ----
#pragma unroll 8
        for (int kk = 0; kk < GKT; ++kk) {
            const float4 a0 = ((const float4*)&Ash[kk][tn * 8])[0];
            const float4 a1 = ((const float4*)&Ash[kk][tn * 8])[1];
            const float4 b0 = ((const float4*)&Bsh[kk][tj * 8])[0];
            const float4 b1 = ((const float4*)&Bsh[kk][tj * 8])[1];
            float a[8] = {a0.x, a0.y, a0.z, a0.w, a1.x, a1.y, a1.z, a1.w};
            float b[8] = {b0.x, b0.y, b0.z, b0.w, b1.x, b1.y, b1.z, b1.w};
#pragma unroll
            for (int i = 0; i < 8; ++i)
#pragma unroll
                for (int j = 0; j < 8; ++j)
                    accr[i][j] = fmaf(a[i], b[j], accr[i][j]);
        }
    }
    // ---- epilogue ----
#pragma unroll
    for (int i = 0; i < 8; ++i) {
        int n = n0 + tn * 8 + i;
        if (n < NN) {
            float4* op = (float4*)(acc + (long long)n * DD + tj * 8);
            float4 r0v, r1v;
            r0v.x = accr[i][0]; r0v.y = accr[i][1]; r0v.z = accr[i][2]; r0v.w = accr[i][3];
            r1v.x = accr[i][4]; r1v.y = accr[i][5]; r1v.z = accr[i][6]; r1v.w = accr[i][7];
            if (accumulate) {
                float4 o0 = op[0], o1 = op[1];
                r0v.x += o0.x; r0v.y += o0.y; r0v.z += o0.z; r0v.w += o0.w;
                r1v.x += o1.x; r1v.y += o1.y; r1v.z += o1.z; r1v.w += o1.w;
            }
            op[0] = r0v; op[1] = r1v;
        }
    }
}

// ---------------- fused bias + relu + layernorm ----------------
__global__ __launch_bounds__(256) void k_ln(
    const float* __restrict__ acc, const float* __restrict__ bias, const float* __restrict__ tpb,
    const float* __restrict__ gamma, const float* __restrict__ beta, float* __restrict__ out)
{
    int row  = blockIdx.x * 4 + (threadIdx.x >> 6);
    int lane = threadIdx.x & 63;
    if (row >= NN) return;
    float2 v = ((const float2*)(acc + (long long)row * DD))[lane];
    int j0 = lane * 2;
    v.x += bias[j0]     + tpb[j0];
    v.y += bias[j0 + 1] + tpb[j0 + 1];
    v.x = fmaxf(v.x, 0.0f);
    v.y = fmaxf(v.y, 0.0f);
    float s  = v.x + v.y;
    float s2 = v.x * v.x + v.y * v.y;
    for (int o = 32; o >= 1; o >>= 1) {
        s  += __shfl_down(s, o, 64);
        s2 += __shfl_down(s2, o, 64);
    }
    s  = __shfl(s, 0, 64);
    s2 = __shfl(s2, 0, 64);
    float mu  = s * (1.0f / DD);
    float var = s2 * (1.0f / DD) - mu * mu;
    float inv = rsqrtf(var + 1e-5f);
    float2 o;
    o.x = (v.x - mu) * inv * gamma[j0]     + beta[j0];
    o.y = (v.y - mu) * inv * gamma[j0 + 1] + beta[j0 + 1];
    ((float2*)(out + (long long)row * DD))[lane] = o;
}

extern "C" void kernel_launch(void* const* d_in, const int* in_sizes, int n_in,
                              void* d_out, int out_size, void* d_ws, size_t ws_size,
                              hipStream_t stream)
{
    const float* x     = (const float*)d_in[0];
    const int*   ei    = (const int*)d_in[1];
    const int*   etype = (const int*)d_in[2];
    const float* etime = (const float*)d_in[3];
    const float* basis = (const float*)d_in[4];
    const float* comp  = (const float*)d_in[5];
    const float* root  = (const float*)d_in[6];
    const float* bias  = (const float*)d_in[7];
    const float* tp_w  = (const float*)d_in[8];
    const float* tp_b  = (const float*)d_in[9];
    const float* gamma = (const float*)d_in[10];
    const float* beta  = (const float*)d_in[11];
    float* out = (float*)d_out;

    char* ws = (char*)d_ws;
    size_t off = 0;
    auto alloc = [&](size_t bytes) -> void* {
        void* p = ws + off;
        off = (off + bytes + 255) & ~(size_t)255;
        return p;
    };
    unsigned* red = (unsigned*)alloc(64);
    float* B   = (float*)alloc((size_t)KROWS * DD * sizeof(float));
    float* cnt = (float*)alloc((size_t)NN * RR * sizeof(float));
    float* deg = (float*)alloc((size_t)NN * sizeof(float));
    float* acc = (float*)alloc((size_t)NN * DD * sizeof(float));
    size_t remain = (ws_size > off) ? (ws_size - off) : 0;
    int C = (int)(remain / ((size_t)NN * DD * sizeof(float)));
    if (C > NREL) C = NREL;
    if (C < 1) C = 1;   // ws too small would be unrecoverable anyway
    float* A = (float*)(ws + off);

    const int* esrc = ei;
    const int* edst = ei + NE;

    hipLaunchKernelGGL(k_init, dim3(1), dim3(64), 0, stream, red);
    hipLaunchKernelGGL(k_minmax, dim3(1024), dim3(256), 0, stream, etime, red);
    hipLaunchKernelGGL(k_sumw, dim3(1024), dim3(256), 0, stream, etime, red);
    hipLaunchKernelGGL(k_buildB, dim3((KROWS * DD + 255) / 256), dim3(256), 0, stream,
                       basis, comp, root, tp_w, B);
    hipMemsetAsync(cnt, 0, (size_t)NN * RR * sizeof(float), stream);
    hipMemsetAsync(deg, 0, (size_t)NN * sizeof(float), stream);

    const int gemmGrid = (NN + GBN - 1) / GBN;

    // base pass: acc = x @ root  (B rows 2176..2303), overwrite
    hipLaunchKernelGGL(k_gemm, dim3(gemmGrid), dim3(256), 0, stream,
                       acc, x, DD, B, NREL * DD, DD, cnt, deg, (const float*)red, 0, 0);

    for (int r0 = 0; r0 < NREL; r0 += C) {
        int r1 = (r0 + C < NREL) ? (r0 + C) : NREL;
        int Cc = r1 - r0;
        hipMemsetAsync(A, 0, (size_t)NN * Cc * DD * sizeof(float), stream);
        hipLaunchKernelGGL(k_scatter, dim3((NE + 7) / 8), dim3(256), 0, stream,
                           x, esrc, edst, etype, etime, red, A, cnt, deg, r0, r1, Cc);
        hipLaunchKernelGGL(k_gemm, dim3(gemmGrid), dim3(256), 0, stream,
                           acc, A, Cc * DD, B, r0 * DD, Cc * DD, cnt, deg,
                           (const float*)red, 1, 1);
    }

    hipLaunchKernelGGL(k_ln, dim3((NN + 3) / 4), dim3(256), 0, stream,
                       acc, bias, tp_b, gamma, beta, out);
}

// Round 3
// 2036.827 us; speedup vs baseline: 3.1311x; 3.1311x over previous
//
#include <hip/hip_runtime.h>
#include <hip/hip_bf16.h>
#include <math.h>

#define NN 50000
#define DD 128
#define RR 16
#define NBASIS 10
#define NE 1600000
#define NRELB 18           // Bt rows: 16 relations + tp_w (16) + root (17)
#define DECAY 0.1f

typedef short bf16x8 __attribute__((ext_vector_type(8)));
typedef float f32x4 __attribute__((ext_vector_type(4)));

__device__ __forceinline__ ushort f2b(float f) {
    unsigned u = __float_as_uint(f);
    unsigned r = (u + 0x7FFFu + ((u >> 16) & 1u)) >> 16;
    return (ushort)r;
}
__device__ __forceinline__ float b2f(ushort u) {
    return __uint_as_float(((unsigned)u) << 16);
}

// ---------------- reduction-slot init ----------------
__global__ void k_init(unsigned* red) {
    if (threadIdx.x == 0) {
        red[0] = 0u;              // max(t) bits (t>=0 so uint order == float order)
        red[1] = 0x7F800000u;     // min(t) bits = +inf
        ((float*)red)[2] = 0.0f;  // sum of unnormalized w
    }
}

__global__ void k_minmax(const float* __restrict__ t, unsigned* red) {
    float mx = 0.0f, mn = 1e30f;
    int stride = gridDim.x * blockDim.x;
    for (int i = blockIdx.x * blockDim.x + threadIdx.x; i < NE; i += stride) {
        float v = t[i];
        mx = fmaxf(mx, v);
        mn = fminf(mn, v);
    }
    for (int o = 32; o >= 1; o >>= 1) {
        mx = fmaxf(mx, __shfl_down(mx, o, 64));
        mn = fminf(mn, __shfl_down(mn, o, 64));
    }
    if ((threadIdx.x & 63) == 0) {
        atomicMax(&red[0], __float_as_uint(mx));
        atomicMin(&red[1], __float_as_uint(mn));
    }
}

__global__ void k_sumw(const float* __restrict__ t, unsigned* red) {
    float tmax = __uint_as_float(red[0]);
    float tmin = __uint_as_float(red[1]);
    float rtd  = 1.0f / (tmax - tmin + 1e-8f);
    float s = 0.0f;
    int stride = gridDim.x * blockDim.x;
    for (int i = blockIdx.x * blockDim.x + threadIdx.x; i < NE; i += stride) {
        s += expf(-DECAY * (tmax - t[i]) * rtd);
    }
    for (int o = 32; o >= 1; o >>= 1) s += __shfl_down(s, o, 64);
    if ((threadIdx.x & 63) == 0) atomicAdd(((float*)red) + 2, s);
}

// ---------------- per-node counts: cnt[n][r], deg[n] ----------------
__global__ void k_cntdeg(const int* __restrict__ edst, const int* __restrict__ etype,
                         float* __restrict__ cnt, float* __restrict__ deg) {
    int e = blockIdx.x * 256 + threadIdx.x;
    if (e >= NE) return;
    int d = edst[e], r = etype[e];
    atomicAdd(&cnt[d * RR + r], 1.0f);
    atomicAdd(&deg[d], 1.0f);
}

// ---------------- build Bt[c][d] (bf16), c = r*128 + j ----------------
// r<16: W[r][d][j] = sum_b comp[r,b]*basis[b,d,j];  r=16: tp_w;  r=17: root
__global__ void k_buildBt(const float* __restrict__ basis, const float* __restrict__ comp,
                          const float* __restrict__ root,  const float* __restrict__ tp_w,
                          ushort* __restrict__ Bt) {
    int idx = blockIdx.x * 256 + threadIdx.x;
    if (idx >= NRELB * DD * DD) return;
    int d = idx & 127, c = idx >> 7;
    int r = c >> 7, j = c & 127;
    float v;
    if (r < RR) {
        v = 0.0f;
        for (int b = 0; b < NBASIS; ++b)
            v = fmaf(comp[r * NBASIS + b], basis[(b * DD + d) * DD + j], v);
    } else if (r == RR) {
        v = tp_w[d * DD + j];
    } else {
        v = root[d * DD + j];
    }
    Bt[idx] = f2b(v);
}

// ---------------- x -> bf16 ----------------
__global__ void k_xb(const float* __restrict__ x, ushort* __restrict__ xb) {
    int i = blockIdx.x * 256 + threadIdx.x;   // one float4 per thread
    if (i >= NN * (DD / 4)) return;
    float4 v = ((const float4*)x)[i];
    ushort4 o;
    o.x = f2b(v.x); o.y = f2b(v.y); o.z = f2b(v.z); o.w = f2b(v.w);
    ((ushort4*)xb)[i] = o;
}

// ---------------- acc[N][128] f32 = xb @ root^T (Bt rows 17*128..) via MFMA ----------------
// A-frag: A[m=lane&15][k=quad*8+j]; B-frag: B[n=lane&15][k=quad*8+j];
// D: row=quad*4+reg, col=lane&15.  (verified layouts, m89/m91)
__global__ __launch_bounds__(256) void k_rootgemm(
    const ushort* __restrict__ xb, const ushort* __restrict__ Bt, float* __restrict__ acc)
{
    const int wave = threadIdx.x >> 6;
    const int lane = threadIdx.x & 63;
    const int quad = lane >> 4;
    const int l16  = lane & 15;
    const int row0 = blockIdx.y * 64 + wave * 16;
    const int col0 = blockIdx.x * 64;

    int row = row0 + l16;
    int rsafe = (row < NN) ? row : 0;

    bf16x8 aF[4];
    const bf16x8* ap = (const bf16x8*)(xb + (size_t)rsafe * DD + quad * 8);
#pragma unroll
    for (int ks = 0; ks < 4; ++ks) aF[ks] = ap[ks * 4];

#pragma unroll
    for (int ct = 0; ct < 4; ++ct) {
        f32x4 a4 = {0.0f, 0.0f, 0.0f, 0.0f};
        const int col = col0 + ct * 16 + l16;                // 0..127
        const int btrow = (RR + 1) * DD + col;               // root block
        const bf16x8* bp = (const bf16x8*)(Bt + (size_t)btrow * DD + quad * 8);
#pragma unroll
        for (int ks = 0; ks < 4; ++ks)
            a4 = __builtin_amdgcn_mfma_f32_16x16x32_bf16(aF[ks], bp[ks * 4], a4, 0, 0, 0);
#pragma unroll
        for (int i = 0; i < 4; ++i) {
            int r = row0 + quad * 4 + i;
            if (r < NN) acc[(size_t)r * DD + col] = a4[i];
        }
    }
}

// ---------------- Y[N][CW] bf16 = xb @ (chunk cols of Bt)^T via MFMA ----------------
// Chunk covers relations [r0, r0+C) plus the time column block (local block C).
// CW = (C+1)*128. gridDim.x = CW/64.
__global__ __launch_bounds__(256) void k_ygemm(
    const ushort* __restrict__ xb, const ushort* __restrict__ Bt, ushort* __restrict__ Y,
    int r0, int C, int CW)
{
    const int wave = threadIdx.x >> 6;
    const int lane = threadIdx.x & 63;
    const int quad = lane >> 4;
    const int l16  = lane & 15;
    const int row0 = blockIdx.y * 64 + wave * 16;
    const int col0 = blockIdx.x * 64;

    int row = row0 + l16;
    int rsafe = (row < NN) ? row : 0;

    bf16x8 aF[4];
    const bf16x8* ap = (const bf16x8*)(xb + (size_t)rsafe * DD + quad * 8);
#pragma unroll
    for (int ks = 0; ks < 4; ++ks) aF[ks] = ap[ks * 4];

#pragma unroll
    for (int ct = 0; ct < 4; ++ct) {
        f32x4 a4 = {0.0f, 0.0f, 0.0f, 0.0f};
        const int cL = col0 + ct * 16 + l16;                 // local col in chunk
        const int blk = cL >> 7;                             // local relation block
        const int btrow = (blk < C) ? ((r0 + blk) * DD + (cL & 127))
                                    : (RR * DD + (cL & 127));   // time block
        const bf16x8* bp = (const bf16x8*)(Bt + (size_t)btrow * DD + quad * 8);
#pragma unroll
        for (int ks = 0; ks < 4; ++ks)
            a4 = __builtin_amdgcn_mfma_f32_16x16x32_bf16(aF[ks], bp[ks * 4], a4, 0, 0, 0);
#pragma unroll
        for (int i = 0; i < 4; ++i) {
            int r = row0 + quad * 4 + i;
            if (r < NN) Y[(size_t)r * CW + cL] = f2b(a4[i]);
        }
    }
}

// ---------------- edge scatter into acc[N][128] (fp32 atomics) ----------------
// One wave per edge; lane handles 2 cols. Only edges with rel in [r0, r0+C).
__global__ __launch_bounds__(256) void k_scatter(
    const ushort* __restrict__ Y,
    const int* __restrict__ esrc, const int* __restrict__ edst,
    const int* __restrict__ etype, const float* __restrict__ etime,
    const unsigned* __restrict__ red,
    const float* __restrict__ cnt, const float* __restrict__ deg,
    float* __restrict__ acc, int r0, int C, int CW)
{
    int wave = threadIdx.x >> 6, lane = threadIdx.x & 63;
    long long e = (long long)blockIdx.x * 4 + wave;
    if (e >= NE) return;
    int rel = etype[e];
    if (rel < r0 || rel >= r0 + C) return;   // owned by another chunk
    int src = esrc[e], dst = edst[e];
    float tmax = __uint_as_float(red[0]);
    float tmin = __uint_as_float(red[1]);
    float sumw = ((const float*)red)[2];
    float w = expf(-DECAY * (tmax - etime[e]) / (tmax - tmin + 1e-8f));
    float s1 = 1.0f / fmaxf(cnt[dst * RR + rel], 1.0f);
    float s2 = w / ((sumw + 1e-8f) * fmaxf(deg[dst], 1.0f));
    const ushort2 yr = *(const ushort2*)(Y + (size_t)src * CW + (rel - r0) * DD + lane * 2);
    const ushort2 yt = *(const ushort2*)(Y + (size_t)src * CW + C * DD + lane * 2);
    float vx = fmaf(s1, b2f(yr.x), s2 * b2f(yt.x));
    float vy = fmaf(s1, b2f(yr.y), s2 * b2f(yt.y));
    float* p = acc + (size_t)dst * DD + lane * 2;
    atomicAdd(p, vx);
    atomicAdd(p + 1, vy);
}

// ---------------- fused (acc + bias + tp_b) -> relu -> layernorm ----------------
__global__ __launch_bounds__(256) void k_ln(
    const float* __restrict__ acc,
    const float* __restrict__ bias, const float* __restrict__ tpb,
    const float* __restrict__ gamma, const float* __restrict__ beta,
    float* __restrict__ out)
{
    int row  = blockIdx.x * 4 + (threadIdx.x >> 6);
    int lane = threadIdx.x & 63;
    if (row >= NN) return;
    int j0 = lane * 2;
    float2 v = ((const float2*)(acc + (size_t)row * DD))[lane];
    v.x += bias[j0]     + tpb[j0];
    v.y += bias[j0 + 1] + tpb[j0 + 1];
    v.x = fmaxf(v.x, 0.0f);
    v.y = fmaxf(v.y, 0.0f);
    float s  = v.x + v.y;
    float s2 = v.x * v.x + v.y * v.y;
    for (int o = 32; o >= 1; o >>= 1) {
        s  += __shfl_down(s, o, 64);
        s2 += __shfl_down(s2, o, 64);
    }
    s  = __shfl(s, 0, 64);
    s2 = __shfl(s2, 0, 64);
    float mu  = s * (1.0f / DD);
    float var = s2 * (1.0f / DD) - mu * mu;
    float inv = rsqrtf(var + 1e-5f);
    float2 o;
    o.x = (v.x - mu) * inv * gamma[j0]     + beta[j0];
    o.y = (v.y - mu) * inv * gamma[j0 + 1] + beta[j0 + 1];
    ((float2*)(out + (size_t)row * DD))[lane] = o;
}

extern "C" void kernel_launch(void* const* d_in, const int* in_sizes, int n_in,
                              void* d_out, int out_size, void* d_ws, size_t ws_size,
                              hipStream_t stream)
{
    const float* x     = (const float*)d_in[0];
    const int*   ei    = (const int*)d_in[1];
    const int*   etype = (const int*)d_in[2];
    const float* etime = (const float*)d_in[3];
    const float* basis = (const float*)d_in[4];
    const float* comp  = (const float*)d_in[5];
    const float* root  = (const float*)d_in[6];
    const float* bias  = (const float*)d_in[7];
    const float* tp_w  = (const float*)d_in[8];
    const float* tp_b  = (const float*)d_in[9];
    const float* gamma = (const float*)d_in[10];
    const float* beta  = (const float*)d_in[11];
    float* out = (float*)d_out;

    char* ws = (char*)d_ws;
    size_t off = 0;
    auto alloc = [&](size_t bytes) -> void* {
        void* p = ws + off;
        off = (off + bytes + 255) & ~(size_t)255;
        return p;
    };
    unsigned* red = (unsigned*)alloc(64);
    float* cnt    = (float*)alloc((size_t)NN * RR * sizeof(float));    //  3.2 MB
    float* deg    = (float*)alloc((size_t)NN * sizeof(float));         //  0.2 MB
    float* acc    = (float*)alloc((size_t)NN * DD * sizeof(float));    // 25.6 MB
    ushort* xb    = (ushort*)alloc((size_t)NN * DD * sizeof(ushort));  // 12.8 MB
    ushort* Bt    = (ushort*)alloc((size_t)NRELB * DD * DD * sizeof(ushort)); // 0.59 MB
    ushort* Y     = (ushort*)(ws + off);

    // Adaptive relation chunking: Y chunk = [NN][(C+1)*128] bf16.
    size_t remain = (ws_size > off) ? (ws_size - off) : 0;
    size_t perBlk = (size_t)NN * DD * sizeof(ushort);                  // 12.8 MB per col-block
    int maxC = (int)(remain / perBlk) - 1;                             // reserve time column
    if (maxC > RR) maxC = RR;
    if (maxC < 1) maxC = 1;

    const int* esrc = ei;
    const int* edst = ei + NE;

    hipLaunchKernelGGL(k_init, dim3(1), dim3(64), 0, stream, red);
    hipLaunchKernelGGL(k_minmax, dim3(1024), dim3(256), 0, stream, etime, red);
    hipLaunchKernelGGL(k_sumw, dim3(1024), dim3(256), 0, stream, etime, red);

    hipMemsetAsync(cnt, 0, (size_t)NN * RR * sizeof(float), stream);
    hipMemsetAsync(deg, 0, (size_t)NN * sizeof(float), stream);
    hipLaunchKernelGGL(k_cntdeg, dim3((NE + 255) / 256), dim3(256), 0, stream,
                       edst, etype, cnt, deg);

    hipLaunchKernelGGL(k_buildBt, dim3((NRELB * DD * DD + 255) / 256), dim3(256), 0, stream,
                       basis, comp, root, tp_w, Bt);
    hipLaunchKernelGGL(k_xb, dim3((NN * (DD / 4) + 255) / 256), dim3(256), 0, stream, x, xb);

    const int rowBlocks = (NN + 63) / 64;

    // acc = x @ root (f32, overwrites — no memset needed)
    hipLaunchKernelGGL(k_rootgemm, dim3(2, rowBlocks), dim3(256), 0, stream, xb, Bt, acc);

    for (int r0 = 0; r0 < RR; r0 += maxC) {
        int C  = (r0 + maxC <= RR) ? maxC : (RR - r0);
        int CW = (C + 1) * DD;
        hipLaunchKernelGGL(k_ygemm, dim3(CW / 64, rowBlocks), dim3(256), 0, stream,
                           xb, Bt, Y, r0, C, CW);
        hipLaunchKernelGGL(k_scatter, dim3((NE + 3) / 4), dim3(256), 0, stream,
                           Y, esrc, edst, etype, etime, red, cnt, deg, acc, r0, C, CW);
    }

    hipLaunchKernelGGL(k_ln, dim3((NN + 3) / 4), dim3(256), 0, stream,
                       acc, bias, tp_b, gamma, beta, out);
}

// Round 4
// 744.254 us; speedup vs baseline: 8.5689x; 2.7367x over previous
//
#include <hip/hip_runtime.h>
#include <hip/hip_bf16.h>
#include <math.h>

#define NN 50000
#define DD 128
#define RR 16
#define NBASIS 10
#define NE 1600000
#define NSEG (NN * RR)        // 800000 segments (dst,rel)
#define NPART ((NSEG + 1023) / 1024)   // 782
#define KTOT 2304             // (16 rel + time + x) * 128
#define DECAY 0.1f

typedef short bf16x8 __attribute__((ext_vector_type(8)));
typedef float f32x4 __attribute__((ext_vector_type(4)));

__device__ __forceinline__ ushort f2b(float f) {
    unsigned u = __float_as_uint(f);
    unsigned r = (u + 0x7FFFu + ((u >> 16) & 1u)) >> 16;
    return (ushort)r;
}
__device__ __forceinline__ float b2f(ushort u) {
    return __uint_as_float(((unsigned)u) << 16);
}

// ---------------- reduction slots ----------------
__global__ void k_init(unsigned* red) {
    if (threadIdx.x == 0) {
        red[0] = 0u;              // max(t) bits (t>=0: uint order == float order)
        red[1] = 0x7F800000u;     // min(t) = +inf
        ((float*)red)[2] = 0.0f;  // sum of unnormalized w
    }
}

__global__ void k_minmax(const float* __restrict__ t, unsigned* red) {
    float mx = 0.0f, mn = 1e30f;
    int stride = gridDim.x * blockDim.x;
    for (int i = blockIdx.x * blockDim.x + threadIdx.x; i < NE; i += stride) {
        float v = t[i];
        mx = fmaxf(mx, v);
        mn = fminf(mn, v);
    }
    for (int o = 32; o >= 1; o >>= 1) {
        mx = fmaxf(mx, __shfl_down(mx, o, 64));
        mn = fminf(mn, __shfl_down(mn, o, 64));
    }
    if ((threadIdx.x & 63) == 0) {
        atomicMax(&red[0], __float_as_uint(mx));
        atomicMin(&red[1], __float_as_uint(mn));
    }
}

__global__ void k_sumw(const float* __restrict__ t, unsigned* red) {
    float tmax = __uint_as_float(red[0]);
    float tmin = __uint_as_float(red[1]);
    float rtd  = 1.0f / (tmax - tmin + 1e-8f);
    float s = 0.0f;
    int stride = gridDim.x * blockDim.x;
    for (int i = blockIdx.x * blockDim.x + threadIdx.x; i < NE; i += stride)
        s += expf(-DECAY * (tmax - t[i]) * rtd);
    for (int o = 32; o >= 1; o >>= 1) s += __shfl_down(s, o, 64);
    if ((threadIdx.x & 63) == 0) atomicAdd(((float*)red) + 2, s);
}

// ---------------- segment histogram ----------------
__global__ void k_cnt(const int* __restrict__ edst, const int* __restrict__ etype,
                      unsigned* __restrict__ cnt) {
    int e = blockIdx.x * 256 + threadIdx.x;
    if (e >= NE) return;
    atomicAdd(&cnt[edst[e] * RR + etype[e]], 1u);
}

// ---------------- hierarchical exclusive scan over cnt[NSEG] ----------------
__global__ __launch_bounds__(1024) void k_scan1(const unsigned* __restrict__ cnt,
                                                unsigned* __restrict__ segptr,
                                                unsigned* __restrict__ part) {
    __shared__ unsigned sh[1024];
    int tid = threadIdx.x;
    int i = blockIdx.x * 1024 + tid;
    unsigned v = (i < NSEG) ? cnt[i] : 0u;
    sh[tid] = v;
    __syncthreads();
    for (int off = 1; off < 1024; off <<= 1) {
        unsigned t = (tid >= off) ? sh[tid - off] : 0u;
        __syncthreads();
        sh[tid] += t;
        __syncthreads();
    }
    if (i < NSEG) segptr[i] = sh[tid] - v;       // exclusive, block-local
    if (tid == 1023) part[blockIdx.x] = sh[1023];
}

__global__ __launch_bounds__(1024) void k_scan2(unsigned* __restrict__ part) {
    __shared__ unsigned sh[1024];
    int tid = threadIdx.x;
    unsigned v = (tid < NPART) ? part[tid] : 0u;
    sh[tid] = v;
    __syncthreads();
    for (int off = 1; off < 1024; off <<= 1) {
        unsigned t = (tid >= off) ? sh[tid - off] : 0u;
        __syncthreads();
        sh[tid] += t;
        __syncthreads();
    }
    if (tid < NPART) part[tid] = sh[tid] - v;    // exclusive
}

__global__ __launch_bounds__(1024) void k_scan3(unsigned* __restrict__ segptr,
                                                const unsigned* __restrict__ part) {
    int i = blockIdx.x * 1024 + threadIdx.x;
    if (i < NSEG) segptr[i] += part[i >> 10];
}

// ---------------- reorder edges into segment-sorted records ----------------
// After this kernel segptr[s] = END of segment s (start = segptr[s-1], or 0).
__global__ void k_reorder(const int* __restrict__ esrc, const int* __restrict__ edst,
                          const int* __restrict__ etype, const float* __restrict__ etime,
                          const unsigned* __restrict__ red,
                          unsigned* __restrict__ segptr,
                          ushort* __restrict__ srcrec, float* __restrict__ wrec) {
    int e = blockIdx.x * 256 + threadIdx.x;
    if (e >= NE) return;
    int seg = edst[e] * RR + etype[e];
    unsigned pos = atomicAdd(&segptr[seg], 1u);
    srcrec[pos] = (ushort)esrc[e];
    float tmax = __uint_as_float(red[0]);
    float tmin = __uint_as_float(red[1]);
    wrec[pos] = expf(-DECAY * (tmax - etime[e]) / (tmax - tmin + 1e-8f));
}

// ---------------- x -> bf16 ----------------
__global__ void k_xb(const float* __restrict__ x, ushort* __restrict__ xb) {
    int i = blockIdx.x * 256 + threadIdx.x;
    if (i >= NN * (DD / 4)) return;
    float4 v = ((const float4*)x)[i];
    ushort4 o;
    o.x = f2b(v.x); o.y = f2b(v.y); o.z = f2b(v.z); o.w = f2b(v.w);
    ((ushort4*)xb)[i] = o;
}

// ---------------- Bt3[j][k] bf16, k = r*128 + d ----------------
// r<16: W_r[d][j]=sum_b comp[r,b]*basis[b,d,j];  r=16: tp_w[d][j];  r=17: root[d][j]
__global__ void k_bt3(const float* __restrict__ basis, const float* __restrict__ comp,
                      const float* __restrict__ root,  const float* __restrict__ tp_w,
                      ushort* __restrict__ Bt3) {
    int idx = blockIdx.x * 256 + threadIdx.x;
    if (idx >= DD * KTOT) return;
    int j = idx / KTOT, k = idx - j * KTOT;
    int r = k >> 7, d = k & 127;
    float v;
    if (r < RR) {
        v = 0.0f;
        for (int b = 0; b < NBASIS; ++b)
            v = fmaf(comp[r * NBASIS + b], basis[(b * DD + d) * DD + j], v);
    } else if (r == RR) {
        v = tp_w[d * DD + j];
    } else {
        v = root[d * DD + j];
    }
    Bt3[idx] = f2b(v);
}

// ---------------- gather-aggregate: one wave per dst node, no atomics ----------------
// A2[dst] = [mean_r0 .. mean_r15, xt*(1/(sumw*deg)), x] each 128 bf16 (KTOT total)
__global__ __launch_bounds__(256) void k_gather(
    const ushort* __restrict__ xb, const ushort* __restrict__ srcrec,
    const float* __restrict__ wrec, const unsigned* __restrict__ cnt,
    const unsigned* __restrict__ segptr, const unsigned* __restrict__ red,
    ushort* __restrict__ A2)
{
    int wave = threadIdx.x >> 6, lane = threadIdx.x & 63;
    int dst = blockIdx.x * 4 + wave;
    if (dst >= NN) return;
    const float sumw = ((const float*)red)[2];
    unsigned s0 = (unsigned)dst * RR;
    unsigned start = (s0 == 0) ? 0u : segptr[s0 - 1];
    float xt0 = 0.0f, xt1 = 0.0f;
    unsigned deg = 0;
    unsigned* arow = (unsigned*)(A2 + (size_t)dst * KTOT);
#pragma unroll 1
    for (int r = 0; r < RR; ++r) {
        unsigned c = cnt[s0 + r];
        float a0 = 0.0f, a1 = 0.0f;
        for (unsigned e = start; e < start + c; ++e) {
            unsigned src = srcrec[e];
            float w = wrec[e];
            unsigned pv = ((const unsigned*)(xb + (size_t)src * DD))[lane];
            float vx = b2f((ushort)(pv & 0xFFFFu));
            float vy = b2f((ushort)(pv >> 16));
            a0 += vx; a1 += vy;
            xt0 = fmaf(w, vx, xt0);
            xt1 = fmaf(w, vy, xt1);
        }
        start += c; deg += c;
        float scl = (c > 0u) ? (1.0f / (float)c) : 0.0f;
        arow[r * 64 + lane] = (unsigned)f2b(a0 * scl) | ((unsigned)f2b(a1 * scl) << 16);
    }
    float s2 = 1.0f / ((sumw + 1e-8f) * fmaxf((float)deg, 1.0f));
    arow[RR * 64 + lane] = (unsigned)f2b(xt0 * s2) | ((unsigned)f2b(xt1 * s2) << 16);
    arow[(RR + 1) * 64 + lane] = ((const unsigned*)(xb + (size_t)dst * DD))[lane];
}

// ---------------- fused GEMM + bias + relu + layernorm ----------------
// Block: 4 waves x 32 rows = 128 rows, 128 cols (full row -> LN in-wave).
// B k-chunk (32x128 bf16 = 8KB) staged in LDS, XOR-swizzled (2-way max).
__global__ __launch_bounds__(256) void k_fgemm(
    const ushort* __restrict__ A2, const ushort* __restrict__ Bt3,
    const float* __restrict__ bias, const float* __restrict__ tpb,
    const float* __restrict__ gamma, const float* __restrict__ beta,
    float* __restrict__ out)
{
    __shared__ uint4 Bs[512];   // slot = col*4 + ((kp+col)&3)
    const int tid  = threadIdx.x;
    const int wave = tid >> 6, lane = tid & 63;
    const int quad = lane >> 4, l16 = lane & 15;
    const int rb = blockIdx.x * 128 + wave * 32;

    f32x4 acc[8][2];
#pragma unroll
    for (int ct = 0; ct < 8; ++ct) {
        acc[ct][0] = (f32x4){0.0f, 0.0f, 0.0f, 0.0f};
        acc[ct][1] = (f32x4){0.0f, 0.0f, 0.0f, 0.0f};
    }

    for (int ks = 0; ks < KTOT / 32; ++ks) {
        const int k0 = ks * 32;
        __syncthreads();
#pragma unroll
        for (int i = 0; i < 2; ++i) {
            int idx = tid + i * 256;          // 0..511
            int col = idx >> 2, kp = idx & 3;
            uint4 v = *(const uint4*)(Bt3 + (size_t)col * KTOT + k0 + kp * 8);
            Bs[col * 4 + ((kp + col) & 3)] = v;
        }
        __syncthreads();
        bf16x8 aF0 = *(const bf16x8*)(A2 + (size_t)(rb + l16) * KTOT + k0 + quad * 8);
        bf16x8 aF1 = *(const bf16x8*)(A2 + (size_t)(rb + 16 + l16) * KTOT + k0 + quad * 8);
#pragma unroll
        for (int ct = 0; ct < 8; ++ct) {
            int col = ct * 16 + l16;
            bf16x8 bF = *(const bf16x8*)&Bs[col * 4 + ((quad + col) & 3)];
            acc[ct][0] = __builtin_amdgcn_mfma_f32_16x16x32_bf16(aF0, bF, acc[ct][0], 0, 0, 0);
            acc[ct][1] = __builtin_amdgcn_mfma_f32_16x16x32_bf16(aF1, bF, acc[ct][1], 0, 0, 0);
        }
    }

    float bcol[8], gcol[8], btc[8];
#pragma unroll
    for (int ct = 0; ct < 8; ++ct) {
        int col = ct * 16 + l16;
        bcol[ct] = bias[col] + tpb[col];
        gcol[ct] = gamma[col];
        btc[ct]  = beta[col];
    }

#pragma unroll
    for (int h = 0; h < 2; ++h) {
        float s[4] = {0, 0, 0, 0}, q[4] = {0, 0, 0, 0};
#pragma unroll
        for (int ct = 0; ct < 8; ++ct)
#pragma unroll
            for (int i = 0; i < 4; ++i) {
                float v = acc[ct][h][i] + bcol[ct];
                v = fmaxf(v, 0.0f);
                acc[ct][h][i] = v;
                s[i] += v;
                q[i] = fmaf(v, v, q[i]);
            }
#pragma unroll
        for (int off = 1; off < 16; off <<= 1)
#pragma unroll
            for (int i = 0; i < 4; ++i) {
                s[i] += __shfl_xor(s[i], off, 64);
                q[i] += __shfl_xor(q[i], off, 64);
            }
#pragma unroll
        for (int i = 0; i < 4; ++i) {
            int row = rb + h * 16 + quad * 4 + i;
            float mu  = s[i] * (1.0f / DD);
            float var = q[i] * (1.0f / DD) - mu * mu;
            float inv = rsqrtf(var + 1e-5f);
            if (row < NN) {
#pragma unroll
                for (int ct = 0; ct < 8; ++ct)
                    out[(size_t)row * DD + ct * 16 + l16] =
                        (acc[ct][h][i] - mu) * inv * gcol[ct] + btc[ct];
            }
        }
    }
}

extern "C" void kernel_launch(void* const* d_in, const int* in_sizes, int n_in,
                              void* d_out, int out_size, void* d_ws, size_t ws_size,
                              hipStream_t stream)
{
    const float* x     = (const float*)d_in[0];
    const int*   ei    = (const int*)d_in[1];
    const int*   etype = (const int*)d_in[2];
    const float* etime = (const float*)d_in[3];
    const float* basis = (const float*)d_in[4];
    const float* comp  = (const float*)d_in[5];
    const float* root  = (const float*)d_in[6];
    const float* bias  = (const float*)d_in[7];
    const float* tp_w  = (const float*)d_in[8];
    const float* tp_b  = (const float*)d_in[9];
    const float* gamma = (const float*)d_in[10];
    const float* beta  = (const float*)d_in[11];
    float* out = (float*)d_out;

    char* ws = (char*)d_ws;
    size_t off = 0;
    auto alloc = [&](size_t bytes) -> void* {
        void* p = ws + off;
        off = (off + bytes + 255) & ~(size_t)255;
        return p;
    };
    unsigned* red    = (unsigned*)alloc(64);
    unsigned* cnt    = (unsigned*)alloc((size_t)NSEG * 4);          //  3.2 MB
    unsigned* segptr = (unsigned*)alloc((size_t)NSEG * 4);          //  3.2 MB
    unsigned* part   = (unsigned*)alloc(1024 * 4);                  //  4 KB
    ushort*   srcrec = (ushort*)alloc((size_t)NE * 2);              //  3.2 MB
    float*    wrec   = (float*)alloc((size_t)NE * 4);               //  6.4 MB
    ushort*   xb     = (ushort*)alloc((size_t)NN * DD * 2);         // 12.8 MB
    ushort*   Bt3    = (ushort*)alloc((size_t)DD * KTOT * 2);       //  0.59 MB
    ushort*   A2     = (ushort*)alloc((size_t)50048 * KTOT * 2);    // 230.6 MB (padded rows)
    (void)ws_size;

    const int* esrc = ei;
    const int* edst = ei + NE;

    hipLaunchKernelGGL(k_init, dim3(1), dim3(64), 0, stream, red);
    hipLaunchKernelGGL(k_minmax, dim3(1024), dim3(256), 0, stream, etime, red);
    hipLaunchKernelGGL(k_sumw, dim3(1024), dim3(256), 0, stream, etime, red);

    hipMemsetAsync(cnt, 0, (size_t)NSEG * 4, stream);
    hipLaunchKernelGGL(k_cnt, dim3((NE + 255) / 256), dim3(256), 0, stream,
                       edst, etype, cnt);

    hipLaunchKernelGGL(k_scan1, dim3(NPART), dim3(1024), 0, stream, cnt, segptr, part);
    hipLaunchKernelGGL(k_scan2, dim3(1), dim3(1024), 0, stream, part);
    hipLaunchKernelGGL(k_scan3, dim3(NPART), dim3(1024), 0, stream, segptr, part);

    hipLaunchKernelGGL(k_reorder, dim3((NE + 255) / 256), dim3(256), 0, stream,
                       esrc, edst, etype, etime, red, segptr, srcrec, wrec);

    hipLaunchKernelGGL(k_xb, dim3((NN * (DD / 4) + 255) / 256), dim3(256), 0, stream, x, xb);
    hipLaunchKernelGGL(k_bt3, dim3((DD * KTOT + 255) / 256), dim3(256), 0, stream,
                       basis, comp, root, tp_w, Bt3);

    hipLaunchKernelGGL(k_gather, dim3((NN + 3) / 4), dim3(256), 0, stream,
                       xb, srcrec, wrec, cnt, segptr, red, A2);

    hipLaunchKernelGGL(k_fgemm, dim3((NN + 127) / 128), dim3(256), 0, stream,
                       A2, Bt3, bias, tp_b, gamma, beta, out);
}